// Round 1
// baseline (149.948 us; speedup 1.0000x reference)
//
#include <hip/hip_runtime.h>

#define W 32          // window taps
#define OPT 16        // outputs per thread
#define BLK 256       // threads per block

__global__ __launch_bounds__(BLK) void wma_kernel(const float* __restrict__ sig,
                                                  const float* __restrict__ wts,
                                                  float* __restrict__ out,
                                                  int T, int blocks_per_row) {
    // Load + normalize weights (uniform address across lanes -> broadcast, L1-hot)
    float w[W];
    float s = 0.0f;
#pragma unroll
    for (int k = 0; k < W; ++k) { w[k] = wts[k]; s += w[k]; }
    float inv = 1.0f / s;
#pragma unroll
    for (int k = 0; k < W; ++k) w[k] *= inv;

    const int c = blockIdx.x / blocks_per_row;
    const int bir = blockIdx.x % blocks_per_row;
    const int t0 = (bir * BLK + threadIdx.x) * OPT;

    const float* __restrict__ row = sig + (long long)c * T;
    const int base = t0 - W;  // multiple of 16 when >= 0 -> 64B aligned

    float buf[OPT + W];  // 48 floats: sig[t0-32 .. t0+15]
    if (base >= 0) {
#pragma unroll
        for (int v = 0; v < (OPT + W) / 4; ++v) {
            float4 f = *reinterpret_cast<const float4*>(row + base + v * 4);
            buf[v * 4 + 0] = f.x;
            buf[v * 4 + 1] = f.y;
            buf[v * 4 + 2] = f.z;
            buf[v * 4 + 3] = f.w;
        }
    } else {
        // only the first two thread-chunks of each row (t0 = 0, 16)
#pragma unroll
        for (int i = 0; i < OPT + W; ++i) {
            int idx = base + i;
            buf[i] = (idx >= 0) ? row[idx] : 0.0f;
        }
    }

    float acc[OPT];
#pragma unroll
    for (int j = 0; j < OPT; ++j) acc[j] = 0.0f;

    // out[t0+j] = sum_k w[k] * sig[t0+j-31+k] ; sig index = base + (j+1+k)
#pragma unroll
    for (int k = 0; k < W; ++k) {
#pragma unroll
        for (int j = 0; j < OPT; ++j) {
            acc[j] = fmaf(w[k], buf[j + 1 + k], acc[j]);
        }
    }

    // first W-1 = 31 outputs of each row are zero
#pragma unroll
    for (int j = 0; j < OPT; ++j) {
        if (t0 + j < W - 1) acc[j] = 0.0f;
    }

    float* __restrict__ orow = out + (long long)c * T + t0;
#pragma unroll
    for (int v = 0; v < OPT / 4; ++v) {
        float4 f = make_float4(acc[v * 4 + 0], acc[v * 4 + 1],
                               acc[v * 4 + 2], acc[v * 4 + 3]);
        *reinterpret_cast<float4*>(orow + v * 4) = f;
    }
}

extern "C" void kernel_launch(void* const* d_in, const int* in_sizes, int n_in,
                              void* d_out, int out_size, void* d_ws, size_t ws_size,
                              hipStream_t stream) {
    const float* sig = (const float*)d_in[0];
    const float* wts = (const float*)d_in[1];
    float* out = (float*)d_out;

    const int C = 256;
    const int T = in_sizes[0] / C;              // 262144
    const int blocks_per_row = T / (OPT * BLK); // 64
    const int grid = C * blocks_per_row;        // 16384

    wma_kernel<<<grid, BLK, 0, stream>>>(sig, wts, out, T, blocks_per_row);
}

// Round 3
// 92.911 us; speedup vs baseline: 1.6139x; 1.6139x over previous
//
#include <hip/hip_runtime.h>

#define W 32          // window taps
#define OPT 8         // outputs per thread (32B lane stride -> near-coalesced)
#define BLK 256       // threads per block

typedef float floatx4 __attribute__((ext_vector_type(4)));

__global__ __launch_bounds__(BLK) void wma_kernel(const float* __restrict__ sig,
                                                  const float* __restrict__ wts,
                                                  float* __restrict__ out,
                                                  int T, int blocks_per_row) {
    // Load + normalize weights (wave-uniform address -> scalar loads / SGPRs)
    float w[W];
    float s = 0.0f;
#pragma unroll
    for (int k = 0; k < W; ++k) { w[k] = wts[k]; s += w[k]; }
    float inv = 1.0f / s;
#pragma unroll
    for (int k = 0; k < W; ++k) w[k] *= inv;

    const int c = blockIdx.x / blocks_per_row;
    const int bir = blockIdx.x % blocks_per_row;
    const int t0 = (bir * BLK + threadIdx.x) * OPT;

    const float* __restrict__ row = sig + (long long)c * T;
    const int base = t0 - W;  // multiple of 8 floats when >= 0 -> 32B aligned

    float buf[OPT + W];  // 40 floats: sig[t0-32 .. t0+7]
    if (base >= 0) {
#pragma unroll
        for (int v = 0; v < (OPT + W) / 4; ++v) {
            floatx4 f = *reinterpret_cast<const floatx4*>(row + base + v * 4);
            buf[v * 4 + 0] = f.x;
            buf[v * 4 + 1] = f.y;
            buf[v * 4 + 2] = f.z;
            buf[v * 4 + 3] = f.w;
        }
    } else {
        // only the first 4 thread-chunks of each row (t0 = 0,8,16,24)
#pragma unroll
        for (int i = 0; i < OPT + W; ++i) {
            int idx = base + i;
            buf[i] = (idx >= 0) ? row[idx] : 0.0f;
        }
    }

    float acc[OPT];
#pragma unroll
    for (int j = 0; j < OPT; ++j) acc[j] = 0.0f;

    // out[t0+j] = sum_k w[k] * sig[t0+j-31+k] ; sig index = base + (j+1+k)
#pragma unroll
    for (int k = 0; k < W; ++k) {
#pragma unroll
        for (int j = 0; j < OPT; ++j) {
            acc[j] = fmaf(w[k], buf[j + 1 + k], acc[j]);
        }
    }

    // first W-1 = 31 outputs of each row are zero
#pragma unroll
    for (int j = 0; j < OPT; ++j) {
        if (t0 + j < W - 1) acc[j] = 0.0f;
    }

    float* __restrict__ orow = out + (long long)c * T + t0;
#pragma unroll
    for (int v = 0; v < OPT / 4; ++v) {
        floatx4 f;
        f.x = acc[v * 4 + 0];
        f.y = acc[v * 4 + 1];
        f.z = acc[v * 4 + 2];
        f.w = acc[v * 4 + 3];
        __builtin_nontemporal_store(f, reinterpret_cast<floatx4*>(orow + v * 4));
    }
}

extern "C" void kernel_launch(void* const* d_in, const int* in_sizes, int n_in,
                              void* d_out, int out_size, void* d_ws, size_t ws_size,
                              hipStream_t stream) {
    const float* sig = (const float*)d_in[0];
    const float* wts = (const float*)d_in[1];
    float* out = (float*)d_out;

    const int C = 256;
    const int T = in_sizes[0] / C;              // 262144
    const int blocks_per_row = T / (OPT * BLK); // 128
    const int grid = C * blocks_per_row;        // 32768

    wma_kernel<<<grid, BLK, 0, stream>>>(sig, wts, out, T, blocks_per_row);
}